// Round 2
// baseline (175.959 us; speedup 1.0000x reference)
//
#include <hip/hip_runtime.h>

// WaveKANLinear: out[n,o] = sum_d mexhat((ln(x)[n,d]-t[o,d])/s[o,d]) * ww[o,d]
//                           + silu(sum_d x[n,d]*bw[o,d])
// N=8192, D=128, O=128, float32.
// R7: main kernel is LDS-read-pipe bound (R1: 70us, 7.8M bank-conflict cy,
//     HBM 1.3%). Changes:
//     (a) 4 rows/thread (was 2): per-lane s_w ds_read_b128 traffic halves
//         (1GB -> 0.5GB device-wide). BLOCK=512 = 128 o x 4 row-groups.
//     (b) XOR-swizzled s_w staging: write col = so^(d&7), read col = o^(dl&7).
//         Kills the 8-way write conflict that was ~12us of the R1 regression.
//     (c) softplus via __logf(1+__expf(-|x|)) (stable, ~10 insts) instead of
//         the slow ocml log1pf library call.
//     No workspace use (harness poison-fill floor is unconditional; d_ws unused).

#define D_DIM 128
#define O_DIM 128
#define ROWS  16     // rows per block
#define BLOCK 512    // 8 waves: o = tid&127, row-group g = tid>>7 (4 rows each)
#define CHUNK 16     // d-rows staged per LDS chunk
#define NCHUNK (D_DIM / CHUNK)

#define C1     0.72134752f   // 0.5*log2(e); exp(-z^2/2) = exp2(-C1*z^2)
#define SQRT_C 0.84932180f   // sqrt(C1)
#define WWK    1.2023651f    // MEX_C / C1, MEX_C = 2/(sqrt(3)*pi^0.25)
#define LOG2E  1.44269504f

typedef float v2f __attribute__((ext_vector_type(2)));

// softplus(scale)+0.1 -> packed wavelet params {t*is2, is2, ww*WWK, bw}
__device__ __forceinline__ float4 wk_transform(float sc, float tr, float w_w, float b_w) {
    // stable for all sc: exp(-|sc|) <= 1, underflow -> log(1)=0 -> sp=max(sc,0)
    float sp  = fmaxf(sc, 0.0f) + __logf(1.0f + __expf(-fabsf(sc)));
    float is2 = SQRT_C / (sp + 0.1f);
    float4 w;
    w.x = tr * is2;
    w.y = is2;
    w.z = w_w * WWK;
    w.w = b_w;
    return w;
}

__global__ __launch_bounds__(BLOCK, 4) void wavekan_main(
    const float* __restrict__ x,
    const float* __restrict__ scale,
    const float* __restrict__ trans,
    const float* __restrict__ ww,
    const float* __restrict__ bw,
    const float* __restrict__ gamma,
    const float* __restrict__ beta,
    float* __restrict__ out,
    int N)
{
    // x staged per d: 4 ln + 4 raw (one float4 each), column-group XOR-swizzled
    // by ((d>>2)&3) so phase-1's stride-256B lane writes spread over 4 slots.
    __shared__ float4 s_ln4[D_DIM * 4];              // 8 KB
    __shared__ float4 s_rw4[D_DIM * 4];              // 8 KB
    // weights [d_local][o], o-column XOR-swizzled by (d_local&7)
    __shared__ float4 s_w[CHUNK * O_DIM];            // 32 KB

    const int tid  = threadIdx.x;
    const int row0 = blockIdx.x * ROWS;

    // ---- Weight staging ids: thread -> (o = tid>>2, d-quad sq = tid&3) ----
    // per wave: 16 o-rows x 64B segments -> fully coalesced 16B/lane loads.
    const int so    = tid >> 2;               // 0..127
    const int sq    = tid & 3;                // 0..3 (d-quad within chunk)
    const int wbase = so * D_DIM + sq * 4;    // + c*CHUNK

    // Chunk-0 raw weight loads (issued early; consumed after phase-1 compute)
    float4 sc4 = *reinterpret_cast<const float4*>(scale + wbase);
    float4 tr4 = *reinterpret_cast<const float4*>(trans + wbase);
    float4 wv4 = *reinterpret_cast<const float4*>(ww    + wbase);
    float4 bv4 = *reinterpret_cast<const float4*>(bw    + wbase);

    // ---- Phase 1: 32 lanes per row (4 elems each), LayerNorm -> LDS ----
    {
        const int r  = tid >> 5;        // local row 0..15
        const int j  = tid & 31;        // lane within row-half
        const int d0 = j * 4;           // 4 elems per lane
        const int grow = row0 + r;

        float4 v4 = make_float4(0.f, 0.f, 0.f, 0.f);
        if (grow < N)
            v4 = *reinterpret_cast<const float4*>(x + (size_t)grow * D_DIM + d0);

        float sum = (v4.x + v4.y) + (v4.z + v4.w);
        float ssq = (v4.x * v4.x + v4.y * v4.y) + (v4.z * v4.z + v4.w * v4.w);
        #pragma unroll
        for (int m = 1; m < 32; m <<= 1) {   // 32-lane butterfly (rows are
            sum += __shfl_xor(sum, m, 64);   // aligned 32-lane groups)
            ssq += __shfl_xor(ssq, m, 64);
        }
        const float mean = sum * (1.0f / D_DIM);
        const float var  = ssq * (1.0f / D_DIM) - mean * mean;
        const float rstd = rsqrtf(var + 1e-5f);

        float4 g4 = *reinterpret_cast<const float4*>(gamma + d0);
        float4 b4 = *reinterpret_cast<const float4*>(beta + d0);

        const int gw = r >> 2;          // row-group 0..3
        const int cw = r & 3;           // row within group
        const int gx = gw ^ (j & 3);    // == gw ^ ((d>>2)&3) for d = d0..d0+3

        float ln0 = (v4.x - mean) * rstd * g4.x + b4.x;
        float ln1 = (v4.y - mean) * rstd * g4.y + b4.y;
        float ln2 = (v4.z - mean) * rstd * g4.z + b4.z;
        float ln3 = (v4.w - mean) * rstd * g4.w + b4.w;

        reinterpret_cast<float*>(&s_ln4[(d0 + 0) * 4 + gx])[cw] = ln0;
        reinterpret_cast<float*>(&s_ln4[(d0 + 1) * 4 + gx])[cw] = ln1;
        reinterpret_cast<float*>(&s_ln4[(d0 + 2) * 4 + gx])[cw] = ln2;
        reinterpret_cast<float*>(&s_ln4[(d0 + 3) * 4 + gx])[cw] = ln3;
        reinterpret_cast<float*>(&s_rw4[(d0 + 0) * 4 + gx])[cw] = v4.x;
        reinterpret_cast<float*>(&s_rw4[(d0 + 1) * 4 + gx])[cw] = v4.y;
        reinterpret_cast<float*>(&s_rw4[(d0 + 2) * 4 + gx])[cw] = v4.z;
        reinterpret_cast<float*>(&s_rw4[(d0 + 3) * 4 + gx])[cw] = v4.w;
    }

    // Transform chunk 0 while phase-1 finishes elsewhere
    float4 wk0 = wk_transform(sc4.x, tr4.x, wv4.x, bv4.x);
    float4 wk1 = wk_transform(sc4.y, tr4.y, wv4.y, bv4.y);
    float4 wk2 = wk_transform(sc4.z, tr4.z, wv4.z, bv4.z);
    float4 wk3 = wk_transform(sc4.w, tr4.w, wv4.w, bv4.w);

    // ---- Phase 2: thread = column o x 4 rows; weights via LDS chunks ----
    const int o = tid & (O_DIM - 1);
    const int g = tid >> 7;  // row-group 0..3 (uniform per wave)

    v2f aw01 = {0.f, 0.f}, aw23 = {0.f, 0.f};
    v2f ab01 = {0.f, 0.f}, ab23 = {0.f, 0.f};

    for (int c = 0; c < NCHUNK; ++c) {
        __syncthreads();              // prev chunk compute done (+phase-1 at c=0)
        {
            const int dlc = sq * 4;
            s_w[(dlc + 0) * O_DIM + (so ^ ((dlc + 0) & 7))] = wk0;
            s_w[(dlc + 1) * O_DIM + (so ^ ((dlc + 1) & 7))] = wk1;
            s_w[(dlc + 2) * O_DIM + (so ^ ((dlc + 2) & 7))] = wk2;
            s_w[(dlc + 3) * O_DIM + (so ^ ((dlc + 3) & 7))] = wk3;
        }

        // issue next chunk's raw loads; transform lands after compute
        const bool more = (c + 1 < NCHUNK);
        if (more) {
            const int off = wbase + (c + 1) * CHUNK;
            sc4 = *reinterpret_cast<const float4*>(scale + off);
            tr4 = *reinterpret_cast<const float4*>(trans + off);
            wv4 = *reinterpret_cast<const float4*>(ww    + off);
            bv4 = *reinterpret_cast<const float4*>(bw    + off);
        }
        __syncthreads();              // staging visible

        #pragma unroll
        for (int dl = 0; dl < CHUNK; ++dl) {
            float4 w  = s_w[dl * O_DIM + (o ^ (dl & 7))];   // per-lane b128,
                                                            // permuted -> conflict-free
            const int gx = g ^ ((dl >> 2) & 3);             // uniform per wave
            float4 xl = s_ln4[(c * CHUNK + dl) * 4 + gx];   // broadcast b128
            float4 xr = s_rw4[(c * CHUNK + dl) * 4 + gx];   // broadcast b128

            v2f u01 = (v2f){xl.x, xl.y} * w.y - w.x;
            v2f u23 = (v2f){xl.z, xl.w} * w.y - w.x;
            v2f q01 = u01 * u01;
            v2f q23 = u23 * u23;
            v2f e01 = {__builtin_amdgcn_exp2f(-q01.x), __builtin_amdgcn_exp2f(-q01.y)};
            v2f e23 = {__builtin_amdgcn_exp2f(-q23.x), __builtin_amdgcn_exp2f(-q23.y)};
            aw01 += ((q01 - C1) * e01) * w.z;
            aw23 += ((q23 - C1) * e23) * w.z;
            ab01 += (v2f){xr.x, xr.y} * w.w;
            ab23 += (v2f){xr.z, xr.w} * w.w;
        }

        if (more) {
            wk0 = wk_transform(sc4.x, tr4.x, wv4.x, bv4.x);
            wk1 = wk_transform(sc4.y, tr4.y, wv4.y, bv4.y);
            wk2 = wk_transform(sc4.z, tr4.z, wv4.z, bv4.z);
            wk3 = wk_transform(sc4.w, tr4.w, wv4.w, bv4.w);
        }
    }

    // ---- Epilogue: out = wavelet + silu(base), 4 rows ----
    {
        const int rb = row0 + g * 4;
        float basev[4] = {ab01.x, ab01.y, ab23.x, ab23.y};
        float wavv[4]  = {aw01.x, aw01.y, aw23.x, aw23.y};
        #pragma unroll
        for (int i = 0; i < 4; ++i) {
            if (rb + i < N) {
                float v   = basev[i];
                float sig = 1.0f / (1.0f + __builtin_amdgcn_exp2f(-LOG2E * v));
                out[(size_t)(rb + i) * O_DIM + o] = wavv[i] + v * sig;
            }
        }
    }
}

extern "C" void kernel_launch(void* const* d_in, const int* in_sizes, int n_in,
                              void* d_out, int out_size, void* d_ws, size_t ws_size,
                              hipStream_t stream) {
    const float* x     = (const float*)d_in[0];
    const float* scale = (const float*)d_in[1];
    const float* trans = (const float*)d_in[2];
    const float* ww    = (const float*)d_in[3];
    const float* bw    = (const float*)d_in[4];
    const float* gamma = (const float*)d_in[5];
    const float* beta  = (const float*)d_in[6];
    float* out = (float*)d_out;

    const int N = in_sizes[0] / D_DIM;       // 8192
    const int grid = (N + ROWS - 1) / ROWS;  // 512

    (void)d_ws; (void)ws_size;               // workspace deliberately unused

    wavekan_main<<<grid, BLOCK, 0, stream>>>(
        x, scale, trans, ww, bw, gamma, beta, out, N);
}

// Round 3
// 104.997 us; speedup vs baseline: 1.6759x; 1.6759x over previous
//
#include <hip/hip_runtime.h>

// WaveKANLinear: out[n,o] = sum_d mexhat((ln(x)[n,d]-t[o,d])/s[o,d]) * ww[o,d]
//                           + silu(sum_d x[n,d]*bw[o,d])
// N=8192, D=128, O=128, float32.
// R8: R2 spilled (WRITE_SIZE 219MB of scratch: 8 float4 weight-prefetch regs
//     held across a 16-deep unrolled loop). Fix: NO registers live across the
//     compute loop -- staging is load->transform->store strictly between
//     barriers; 3 blocks/CU (48KB LDS) hide the staging latency via
//     inter-block overlap. 8 rows/thread (BLOCK=256) halves per-lane s_w
//     ds_read_b128 traffic vs R2. Keep XOR swizzle (conflicts 7.8M->1.5M in
//     R2) + fast softplus. bench = main + ~56us harness floor.

#define D_DIM 128
#define O_DIM 128
#define ROWS  16     // rows per block
#define BLOCK 256    // 4 waves: o = tid&127, group g = tid>>7 (8 rows each)
#define CHUNK 16     // d-rows staged per LDS chunk
#define NCHUNK (D_DIM / CHUNK)

#define C1     0.72134752f   // 0.5*log2(e); exp(-z^2/2) = exp2(-C1*z^2)
#define SQRT_C 0.84932180f   // sqrt(C1)
#define WWK    1.2023651f    // MEX_C / C1, MEX_C = 2/(sqrt(3)*pi^0.25)
#define LOG2E  1.44269504f

typedef float v2f __attribute__((ext_vector_type(2)));

// softplus(scale)+0.1 -> packed wavelet params {t*is2, is2, ww*WWK, bw}
__device__ __forceinline__ float4 wk_transform(float sc, float tr, float w_w, float b_w) {
    // stable: exp(-|sc|) <= 1; underflow -> log(1)=0 -> sp = max(sc,0)
    float sp  = fmaxf(sc, 0.0f) + __logf(1.0f + __expf(-fabsf(sc)));
    float is2 = SQRT_C / (sp + 0.1f);
    float4 w;
    w.x = tr * is2;
    w.y = is2;
    w.z = w_w * WWK;
    w.w = b_w;
    return w;
}

__global__ __launch_bounds__(BLOCK, 3) void wavekan_main(
    const float* __restrict__ x,
    const float* __restrict__ scale,
    const float* __restrict__ trans,
    const float* __restrict__ ww,
    const float* __restrict__ bw,
    const float* __restrict__ gamma,
    const float* __restrict__ beta,
    float* __restrict__ out,
    int N)
{
    // x staged per d as 4 quads (16 rows): slot gx = quad ^ ((d>>2)&3).
    __shared__ float4 s_ln4[D_DIM * 4];              // 8 KB
    __shared__ float4 s_rw4[D_DIM * 4];              // 8 KB
    // weights [d_local][o], o-column XOR-swizzled by (d_local&7)
    __shared__ float4 s_w[CHUNK * O_DIM];            // 32 KB

    const int tid  = threadIdx.x;
    const int row0 = blockIdx.x * ROWS;

    // ---- Phase 1: 16 rows in 2 passes; 32 lanes x 4 elems per row ----
    {
        const int rA = tid >> 5;        // 0..7
        const int j  = tid & 31;
        const int d0 = j * 4;

        const int gA = row0 + rA;
        const int gB = row0 + 8 + rA;
        float4 vA = make_float4(0.f, 0.f, 0.f, 0.f);
        float4 vB = make_float4(0.f, 0.f, 0.f, 0.f);
        if (gA < N) vA = *reinterpret_cast<const float4*>(x + (size_t)gA * D_DIM + d0);
        if (gB < N) vB = *reinterpret_cast<const float4*>(x + (size_t)gB * D_DIM + d0);
        float4 g4 = *reinterpret_cast<const float4*>(gamma + d0);
        float4 b4 = *reinterpret_cast<const float4*>(beta + d0);

        #pragma unroll
        for (int pass = 0; pass < 2; ++pass) {
            const int r  = pass * 8 + rA;
            float4 v4 = pass ? vB : vA;

            float sum = (v4.x + v4.y) + (v4.z + v4.w);
            float ssq = (v4.x * v4.x + v4.y * v4.y) + (v4.z * v4.z + v4.w * v4.w);
            #pragma unroll
            for (int m = 1; m < 32; m <<= 1) {   // 32-lane butterfly
                sum += __shfl_xor(sum, m, 64);
                ssq += __shfl_xor(ssq, m, 64);
            }
            const float mean = sum * (1.0f / D_DIM);
            const float var  = ssq * (1.0f / D_DIM) - mean * mean;
            const float rstd = rsqrtf(var + 1e-5f);

            const int q  = r >> 2;          // quad 0..3
            const int cw = r & 3;           // row within quad
            const int gx = q ^ (j & 3);     // == q ^ ((d>>2)&3) for d = d0..d0+3

            reinterpret_cast<float*>(&s_ln4[(d0 + 0) * 4 + gx])[cw] = (v4.x - mean) * rstd * g4.x + b4.x;
            reinterpret_cast<float*>(&s_ln4[(d0 + 1) * 4 + gx])[cw] = (v4.y - mean) * rstd * g4.y + b4.y;
            reinterpret_cast<float*>(&s_ln4[(d0 + 2) * 4 + gx])[cw] = (v4.z - mean) * rstd * g4.z + b4.z;
            reinterpret_cast<float*>(&s_ln4[(d0 + 3) * 4 + gx])[cw] = (v4.w - mean) * rstd * g4.w + b4.w;
            reinterpret_cast<float*>(&s_rw4[(d0 + 0) * 4 + gx])[cw] = v4.x;
            reinterpret_cast<float*>(&s_rw4[(d0 + 1) * 4 + gx])[cw] = v4.y;
            reinterpret_cast<float*>(&s_rw4[(d0 + 2) * 4 + gx])[cw] = v4.z;
            reinterpret_cast<float*>(&s_rw4[(d0 + 3) * 4 + gx])[cw] = v4.w;
        }
    }

    // ---- Weight staging ids: thread -> (o = tid>>1, d-octet sq = tid&1) ----
    const int so    = tid >> 1;               // 0..127
    const int sq    = tid & 1;                // 0..1
    const int wbase = so * D_DIM + sq * 8;    // + c*CHUNK

    // ---- Phase 2: thread = column o x 8 rows ----
    const int o = tid & (O_DIM - 1);
    const int g = tid >> 7;  // row-group 0..1 (8 rows), uniform per wave

    v2f aw0 = {0.f,0.f}, aw1 = {0.f,0.f}, aw2 = {0.f,0.f}, aw3 = {0.f,0.f};
    v2f ab0 = {0.f,0.f}, ab1 = {0.f,0.f}, ab2 = {0.f,0.f}, ab3 = {0.f,0.f};

    for (int c = 0; c < NCHUNK; ++c) {
        __syncthreads();              // prev chunk compute done (+phase-1 at c=0)

        // Stage: load -> transform -> store, nothing held across compute.
        {
            const int off = wbase + c * CHUNK;
            float4 s0 = *reinterpret_cast<const float4*>(scale + off);
            float4 s1 = *reinterpret_cast<const float4*>(scale + off + 4);
            float4 t0 = *reinterpret_cast<const float4*>(trans + off);
            float4 t1 = *reinterpret_cast<const float4*>(trans + off + 4);
            float4 w0 = *reinterpret_cast<const float4*>(ww    + off);
            float4 w1 = *reinterpret_cast<const float4*>(ww    + off + 4);
            float4 b0 = *reinterpret_cast<const float4*>(bw    + off);
            float4 b1 = *reinterpret_cast<const float4*>(bw    + off + 4);
            const int db = sq * 8;
            s_w[(db + 0) * O_DIM + (so ^ ((db + 0) & 7))] = wk_transform(s0.x, t0.x, w0.x, b0.x);
            s_w[(db + 1) * O_DIM + (so ^ ((db + 1) & 7))] = wk_transform(s0.y, t0.y, w0.y, b0.y);
            s_w[(db + 2) * O_DIM + (so ^ ((db + 2) & 7))] = wk_transform(s0.z, t0.z, w0.z, b0.z);
            s_w[(db + 3) * O_DIM + (so ^ ((db + 3) & 7))] = wk_transform(s0.w, t0.w, w0.w, b0.w);
            s_w[(db + 4) * O_DIM + (so ^ ((db + 4) & 7))] = wk_transform(s1.x, t1.x, w1.x, b1.x);
            s_w[(db + 5) * O_DIM + (so ^ ((db + 5) & 7))] = wk_transform(s1.y, t1.y, w1.y, b1.y);
            s_w[(db + 6) * O_DIM + (so ^ ((db + 6) & 7))] = wk_transform(s1.z, t1.z, w1.z, b1.z);
            s_w[(db + 7) * O_DIM + (so ^ ((db + 7) & 7))] = wk_transform(s1.w, t1.w, w1.w, b1.w);
        }
        __syncthreads();              // staging visible

        #pragma unroll
        for (int dl = 0; dl < CHUNK; ++dl) {
            float4 w  = s_w[dl * O_DIM + (o ^ (dl & 7))];   // per-lane b128, permuted
            const int di = (c * CHUNK + dl) * 4;
            const int q0 = (2 * g)     ^ ((dl >> 2) & 3);   // uniform per wave
            const int q1 = q0 ^ 1;
            float4 xl0 = s_ln4[di + q0];                    // broadcast b128 x4
            float4 xl1 = s_ln4[di + q1];
            float4 xr0 = s_rw4[di + q0];
            float4 xr1 = s_rw4[di + q1];

            v2f u, qq, e;
            u = (v2f){xl0.x, xl0.y} * w.y - w.x; qq = u * u;
            e = (v2f){__builtin_amdgcn_exp2f(-qq.x), __builtin_amdgcn_exp2f(-qq.y)};
            aw0 += ((qq - C1) * e) * w.z;
            u = (v2f){xl0.z, xl0.w} * w.y - w.x; qq = u * u;
            e = (v2f){__builtin_amdgcn_exp2f(-qq.x), __builtin_amdgcn_exp2f(-qq.y)};
            aw1 += ((qq - C1) * e) * w.z;
            u = (v2f){xl1.x, xl1.y} * w.y - w.x; qq = u * u;
            e = (v2f){__builtin_amdgcn_exp2f(-qq.x), __builtin_amdgcn_exp2f(-qq.y)};
            aw2 += ((qq - C1) * e) * w.z;
            u = (v2f){xl1.z, xl1.w} * w.y - w.x; qq = u * u;
            e = (v2f){__builtin_amdgcn_exp2f(-qq.x), __builtin_amdgcn_exp2f(-qq.y)};
            aw3 += ((qq - C1) * e) * w.z;

            ab0 += (v2f){xr0.x, xr0.y} * w.w;
            ab1 += (v2f){xr0.z, xr0.w} * w.w;
            ab2 += (v2f){xr1.x, xr1.y} * w.w;
            ab3 += (v2f){xr1.z, xr1.w} * w.w;
        }
    }

    // ---- Epilogue: out = wavelet + silu(base), 8 rows ----
    {
        const int rb = row0 + g * 8;
        float wavv[8]  = {aw0.x, aw0.y, aw1.x, aw1.y, aw2.x, aw2.y, aw3.x, aw3.y};
        float basev[8] = {ab0.x, ab0.y, ab1.x, ab1.y, ab2.x, ab2.y, ab3.x, ab3.y};
        #pragma unroll
        for (int i = 0; i < 8; ++i) {
            if (rb + i < N) {
                float v   = basev[i];
                float sig = 1.0f / (1.0f + __builtin_amdgcn_exp2f(-LOG2E * v));
                out[(size_t)(rb + i) * O_DIM + o] = wavv[i] + v * sig;
            }
        }
    }
}

extern "C" void kernel_launch(void* const* d_in, const int* in_sizes, int n_in,
                              void* d_out, int out_size, void* d_ws, size_t ws_size,
                              hipStream_t stream) {
    const float* x     = (const float*)d_in[0];
    const float* scale = (const float*)d_in[1];
    const float* trans = (const float*)d_in[2];
    const float* ww    = (const float*)d_in[3];
    const float* bw    = (const float*)d_in[4];
    const float* gamma = (const float*)d_in[5];
    const float* beta  = (const float*)d_in[6];
    float* out = (float*)d_out;

    const int N = in_sizes[0] / D_DIM;       // 8192
    const int grid = (N + ROWS - 1) / ROWS;  // 512

    (void)d_ws; (void)ws_size;               // workspace deliberately unused

    wavekan_main<<<grid, BLOCK, 0, stream>>>(
        x, scale, trans, ww, bw, gamma, beta, out, N);
}

// Round 4
// 101.279 us; speedup vs baseline: 1.7374x; 1.0367x over previous
//
#include <hip/hip_runtime.h>

// WaveKANLinear: out[n,o] = sum_d mexhat((ln(x)[n,d]-t[o,d])/s[o,d]) * ww[o,d]
//                           + silu(sum_d x[n,d]*bw[o,d])
// N=8192, D=128, O=128, float32.
// R9: R3 was latency-bound at 17% occupancy (2 blk/CU x 4 waves = 2 waves/SIMD;
//     VALUBusy 53% with both pipes modeled ~12us). Fixes:
//     (a) ROWS=8, grid=1024 -> 4 blk/CU (40KB LDS each = 160KB exactly),
//         16 waves/CU = 4/SIMD.
//     (b) prep kernel restored: bench floor ~56us is ONE unconditional d_ws
//         poison fill (R0..R3 arithmetic) -> workspace use is free. Weights
//         pre-transformed to [d][o] float4 -> staging is a pure linear copy,
//         conflict-free writes AND reads, zero transform VALU in main loop.
//     (c) accums shrink to 8 VGPRs (4 rows/thread), no regs live across
//         barriers -> no spill risk at the 128-VGPR/4-wave budget.

#define D_DIM 128
#define O_DIM 128
#define ROWS  8      // rows per block
#define BLOCK 256    // 4 waves: o = tid&127, group g = tid>>7 (4 rows each)
#define CHUNK 16     // d-rows staged per LDS chunk
#define NCHUNK (D_DIM / CHUNK)

#define C1     0.72134752f   // 0.5*log2(e); exp(-z^2/2) = exp2(-C1*z^2)
#define SQRT_C 0.84932180f   // sqrt(C1)
#define WWK    1.2023651f    // MEX_C / C1, MEX_C = 2/(sqrt(3)*pi^0.25)
#define LOG2E  1.44269504f

typedef float v2f __attribute__((ext_vector_type(2)));

// softplus(scale)+0.1 -> packed wavelet params {t*is2, is2, ww*WWK, bw}
__device__ __forceinline__ float4 wk_transform(float sc, float tr, float w_w, float b_w) {
    // stable: exp(-|sc|) <= 1; underflow -> log(1)=0 -> sp = max(sc,0)
    float sp  = fmaxf(sc, 0.0f) + __logf(1.0f + __expf(-fabsf(sc)));
    float is2 = SQRT_C / (sp + 0.1f);
    float4 w;
    w.x = tr * is2;
    w.y = is2;
    w.z = w_w * WWK;
    w.w = b_w;
    return w;
}

// Prep: transpose + transform weights to [d][o] float4 (256 KB in d_ws)
__global__ __launch_bounds__(256) void wavekan_prep(
    const float* __restrict__ scale,
    const float* __restrict__ trans,
    const float* __restrict__ ww,
    const float* __restrict__ bw,
    float4* __restrict__ wsW)
{
    int idx = blockIdx.x * blockDim.x + threadIdx.x;   // = o*128 + d
    if (idx >= O_DIM * D_DIM) return;
    int o = idx >> 7;
    int d = idx & (D_DIM - 1);
    wsW[d * O_DIM + o] = wk_transform(scale[idx], trans[idx], ww[idx], bw[idx]);
}

template<bool USE_WS>
__global__ __launch_bounds__(BLOCK, 4) void wavekan_main(
    const float* __restrict__ x,
    const float* __restrict__ scale,
    const float* __restrict__ trans,
    const float* __restrict__ ww,
    const float* __restrict__ bw,
    const float* __restrict__ gamma,
    const float* __restrict__ beta,
    const float4* __restrict__ wsW,
    float* __restrict__ out,
    int N)
{
    // x staged per d as 2 quads (8 rows): slot gx = quad ^ ((d>>2)&1).
    __shared__ float4 s_ln4[D_DIM * 2];              // 4 KB
    __shared__ float4 s_rw4[D_DIM * 2];              // 4 KB
    // weights [d_local][o] float4, linear (prep already transposed)
    __shared__ float4 s_w[CHUNK * O_DIM];            // 32 KB

    const int tid  = threadIdx.x;
    const int row0 = blockIdx.x * ROWS;

    // ---- Phase 1: 8 rows; 32 lanes x 4 elems per row, LayerNorm -> LDS ----
    {
        const int r  = tid >> 5;        // local row 0..7
        const int j  = tid & 31;
        const int d0 = j * 4;
        const int grow = row0 + r;

        float4 v4 = make_float4(0.f, 0.f, 0.f, 0.f);
        if (grow < N)
            v4 = *reinterpret_cast<const float4*>(x + (size_t)grow * D_DIM + d0);

        float sum = (v4.x + v4.y) + (v4.z + v4.w);
        float ssq = (v4.x * v4.x + v4.y * v4.y) + (v4.z * v4.z + v4.w * v4.w);
        #pragma unroll
        for (int m = 1; m < 32; m <<= 1) {   // 32-lane butterfly (row-aligned)
            sum += __shfl_xor(sum, m, 64);
            ssq += __shfl_xor(ssq, m, 64);
        }
        const float mean = sum * (1.0f / D_DIM);
        const float var  = ssq * (1.0f / D_DIM) - mean * mean;
        const float rstd = rsqrtf(var + 1e-5f);

        float4 g4 = *reinterpret_cast<const float4*>(gamma + d0);
        float4 b4 = *reinterpret_cast<const float4*>(beta + d0);

        const int q  = r >> 2;          // quad 0..1
        const int cw = r & 3;           // row within quad
        const int gx = q ^ (j & 1);     // == q ^ ((d>>2)&1) for d = d0..d0+3

        reinterpret_cast<float*>(&s_ln4[(d0 + 0) * 2 + gx])[cw] = (v4.x - mean) * rstd * g4.x + b4.x;
        reinterpret_cast<float*>(&s_ln4[(d0 + 1) * 2 + gx])[cw] = (v4.y - mean) * rstd * g4.y + b4.y;
        reinterpret_cast<float*>(&s_ln4[(d0 + 2) * 2 + gx])[cw] = (v4.z - mean) * rstd * g4.z + b4.z;
        reinterpret_cast<float*>(&s_ln4[(d0 + 3) * 2 + gx])[cw] = (v4.w - mean) * rstd * g4.w + b4.w;
        reinterpret_cast<float*>(&s_rw4[(d0 + 0) * 2 + gx])[cw] = v4.x;
        reinterpret_cast<float*>(&s_rw4[(d0 + 1) * 2 + gx])[cw] = v4.y;
        reinterpret_cast<float*>(&s_rw4[(d0 + 2) * 2 + gx])[cw] = v4.z;
        reinterpret_cast<float*>(&s_rw4[(d0 + 3) * 2 + gx])[cw] = v4.w;
    }

    // ---- Phase 2: thread = column o x 4 rows ----
    const int o = tid & (O_DIM - 1);
    const int g = tid >> 7;  // row-group 0..1 (4 rows), uniform per wave

    v2f aw0 = {0.f,0.f}, aw1 = {0.f,0.f};
    v2f ab0 = {0.f,0.f}, ab1 = {0.f,0.f};

    for (int c = 0; c < NCHUNK; ++c) {
        __syncthreads();              // prev chunk compute done (+phase-1 at c=0)

        if (USE_WS) {
            // Linear copy ws -> s_w: conflict-free b128 loads AND stores.
            #pragma unroll
            for (int k = 0; k < (CHUNK * O_DIM) / BLOCK; ++k)
                s_w[k * BLOCK + tid] = wsW[c * (CHUNK * O_DIM) + k * BLOCK + tid];
        } else {
            // Fallback: transform inline (write conflicts OK; correctness path)
            const int so = tid & 127;
            const int sq = tid >> 7;
            #pragma unroll
            for (int k = 0; k < 8; ++k) {
                const int dloc = sq * 8 + k;
                const int idx  = so * D_DIM + c * CHUNK + dloc;
                s_w[dloc * O_DIM + so] =
                    wk_transform(scale[idx], trans[idx], ww[idx], bw[idx]);
            }
        }
        __syncthreads();              // staging visible

        #pragma unroll
        for (int dl = 0; dl < CHUNK; ++dl) {
            float4 w  = s_w[dl * O_DIM + o];            // per-lane b128, linear
            const int di = (c * CHUNK + dl) * 2;
            const int gx = g ^ ((dl >> 2) & 1);         // uniform per wave
            float4 xl = s_ln4[di + gx];                 // broadcast b128
            float4 xr = s_rw4[di + gx];                 // broadcast b128

            v2f u, qq, e;
            u = (v2f){xl.x, xl.y} * w.y - w.x; qq = u * u;
            e = (v2f){__builtin_amdgcn_exp2f(-qq.x), __builtin_amdgcn_exp2f(-qq.y)};
            aw0 += ((qq - C1) * e) * w.z;
            u = (v2f){xl.z, xl.w} * w.y - w.x; qq = u * u;
            e = (v2f){__builtin_amdgcn_exp2f(-qq.x), __builtin_amdgcn_exp2f(-qq.y)};
            aw1 += ((qq - C1) * e) * w.z;

            ab0 += (v2f){xr.x, xr.y} * w.w;
            ab1 += (v2f){xr.z, xr.w} * w.w;
        }
    }

    // ---- Epilogue: out = wavelet + silu(base), 4 rows ----
    {
        const int rb = row0 + g * 4;
        float wavv[4]  = {aw0.x, aw0.y, aw1.x, aw1.y};
        float basev[4] = {ab0.x, ab0.y, ab1.x, ab1.y};
        #pragma unroll
        for (int i = 0; i < 4; ++i) {
            if (rb + i < N) {
                float v   = basev[i];
                float sig = 1.0f / (1.0f + __builtin_amdgcn_exp2f(-LOG2E * v));
                out[(size_t)(rb + i) * O_DIM + o] = wavv[i] + v * sig;
            }
        }
    }
}

extern "C" void kernel_launch(void* const* d_in, const int* in_sizes, int n_in,
                              void* d_out, int out_size, void* d_ws, size_t ws_size,
                              hipStream_t stream) {
    const float* x     = (const float*)d_in[0];
    const float* scale = (const float*)d_in[1];
    const float* trans = (const float*)d_in[2];
    const float* ww    = (const float*)d_in[3];
    const float* bw    = (const float*)d_in[4];
    const float* gamma = (const float*)d_in[5];
    const float* beta  = (const float*)d_in[6];
    float* out = (float*)d_out;

    const int N = in_sizes[0] / D_DIM;       // 8192
    const int grid = (N + ROWS - 1) / ROWS;  // 1024

    const size_t ws_needed = (size_t)O_DIM * D_DIM * sizeof(float4);  // 256 KB
    if (ws_size >= ws_needed) {
        wavekan_prep<<<(O_DIM * D_DIM + 255) / 256, 256, 0, stream>>>(
            scale, trans, ww, bw, (float4*)d_ws);
        wavekan_main<true><<<grid, BLOCK, 0, stream>>>(
            x, scale, trans, ww, bw, gamma, beta, (const float4*)d_ws, out, N);
    } else {
        wavekan_main<false><<<grid, BLOCK, 0, stream>>>(
            x, scale, trans, ww, bw, gamma, beta, nullptr, out, N);
    }
}

// Round 5
// 101.146 us; speedup vs baseline: 1.7397x; 1.0013x over previous
//
#include <hip/hip_runtime.h>

// WaveKANLinear: out[n,o] = sum_d mexhat((ln(x)[n,d]-t[o,d])/s[o,d]) * ww[o,d]
//                           + silu(sum_d x[n,d]*bw[o,d])
// N=8192, D=128, O=128, float32.
// R10: R3/R4 proved the barrier-chunked LDS-weights structure is latency-bound
//      (42.6us at 26% occ / 43% VALUBusy; occupancy can't be raised without
//      losing LDS or VGPRs). Invert it: WEIGHTS IN REGISTERS (32 float4 =
//      128 VGPR per thread = its (o, 32-d-slice)), x in LDS. Hot loop has
//      ZERO per-lane LDS reads -- only 4-address multicast x reads -- and
//      8 groups x 32 rows of independent chains, so ILP (not occupancy)
//      hides latency. One barrier per block total. VALU floor ~11-12us
//      (exp2-dominated). Bench floor ~56.7us = one unconditional ws poison
//      fill (R0-R4 arithmetic) -> prep kernel + d_ws stay (free).
//      Spill control: row loop pinned unroll 1 (unroll 2 => >256 VGPR).

#define D_DIM 128
#define O_DIM 128
#define ROWS  32     // rows per block
#define BLOCK 512    // 8 waves; o = wv*16 + (lane&15), dg = lane>>4
#define XPAD  289    // f4 stride of one dg block: 32 rows * 9 + 1 (bank spread)

#define C1     0.72134752f   // 0.5*log2(e); exp(-z^2/2) = exp2(-C1*z^2)
#define SQRT_C 0.84932180f   // sqrt(C1)
#define WWK    1.2023651f    // MEX_C / C1, MEX_C = 2/(sqrt(3)*pi^0.25)
#define LOG2E  1.44269504f

typedef float v2f __attribute__((ext_vector_type(2)));

// softplus(scale)+0.1 -> {t*is2, is2, ww*WWK, bw}
__device__ __forceinline__ void wk_pair(float sc, float tr, float w_w, float b_w,
                                        float& wx, float& wy, float& wz, float& wb) {
    float sp  = fmaxf(sc, 0.0f) + __logf(1.0f + __expf(-fabsf(sc)));  // stable
    float is2 = SQRT_C / (sp + 0.1f);
    wx = tr * is2; wy = is2; wz = w_w * WWK; wb = b_w;
}

// Prep: SoA d-pair layout. For d-pair p (d=2p,2p+1), column o:
//   ws[(p*O+o)*2+0] = {wx0,wx1,wy0,wy1}
//   ws[(p*O+o)*2+1] = {wz0,wz1,wb0,wb1}
// Main thread (o,dg) then loads 16 consecutive-pair 32B packets: v2f-ready.
__global__ __launch_bounds__(256) void wavekan_prep(
    const float* __restrict__ scale,
    const float* __restrict__ trans,
    const float* __restrict__ ww,
    const float* __restrict__ bw,
    float4* __restrict__ wsW)
{
    int idx = blockIdx.x * blockDim.x + threadIdx.x;   // = o*64 + p
    if (idx >= O_DIM * (D_DIM / 2)) return;
    int o = idx >> 6;
    int p = idx & 63;
    int i0 = o * D_DIM + p * 2;
    float wx0, wy0, wz0, wb0, wx1, wy1, wz1, wb1;
    wk_pair(scale[i0],     trans[i0],     ww[i0],     bw[i0],     wx0, wy0, wz0, wb0);
    wk_pair(scale[i0 + 1], trans[i0 + 1], ww[i0 + 1], bw[i0 + 1], wx1, wy1, wz1, wb1);
    wsW[(p * O_DIM + o) * 2 + 0] = make_float4(wx0, wx1, wy0, wy1);
    wsW[(p * O_DIM + o) * 2 + 1] = make_float4(wz0, wz1, wb0, wb1);
}

template<bool USE_WS>
__global__ __launch_bounds__(BLOCK, 2) void wavekan_main(
    const float* __restrict__ x,
    const float* __restrict__ scale,
    const float* __restrict__ trans,
    const float* __restrict__ ww,
    const float* __restrict__ bw,
    const float* __restrict__ gamma,
    const float* __restrict__ beta,
    const float4* __restrict__ wsW,
    float* __restrict__ out,
    int N)
{
    // x staged once for all 32 rows. [dg][row][8 f4] with +1 f4/row pad and
    // +1 f4/dg-block pad: multicast reads (4 dg addresses/wave) land on
    // disjoint bank quads; LN writes <=2-way.
    __shared__ float4 s_ln4[4 * XPAD];               // 18.1 KB
    __shared__ float4 s_rw4[4 * XPAD];               // 18.1 KB

    const int tid  = threadIdx.x;
    const int lane = tid & 63;
    const int wv   = tid >> 6;                       // wave 0..7
    const int o    = wv * 16 + (lane & 15);          // output column
    const int dg   = lane >> 4;                      // d-group 0..3 (32 d each)
    const int row0 = blockIdx.x * ROWS;

    // ---- Weight regs: 16 d-pairs x 2 f4 = 128 VGPR (static-indexed) ----
    float4 wA[16], wB[16];
    if (USE_WS) {
        #pragma unroll
        for (int k = 0; k < 16; ++k) {
            const int p = dg * 16 + k;
            wA[k] = wsW[(p * O_DIM + o) * 2 + 0];
            wB[k] = wsW[(p * O_DIM + o) * 2 + 1];
        }
    } else {
        #pragma unroll
        for (int k = 0; k < 16; ++k) {
            const int i0 = o * D_DIM + dg * 32 + 2 * k;
            float wx0, wy0, wz0, wb0, wx1, wy1, wz1, wb1;
            wk_pair(scale[i0],     trans[i0],     ww[i0],     bw[i0],     wx0, wy0, wz0, wb0);
            wk_pair(scale[i0 + 1], trans[i0 + 1], ww[i0 + 1], bw[i0 + 1], wx1, wy1, wz1, wb1);
            wA[k] = make_float4(wx0, wx1, wy0, wy1);
            wB[k] = make_float4(wz0, wz1, wb0, wb1);
        }
    }

    // ---- Phase 1: LN of 32 rows. 16 lanes x 8 elems per row. ----
    {
        const int r    = tid >> 4;       // local row 0..31
        const int j    = tid & 15;       // lane within row group
        const int d0   = j * 8;
        const int grow = row0 + r;

        float4 va = make_float4(0.f, 0.f, 0.f, 0.f);
        float4 vb = make_float4(0.f, 0.f, 0.f, 0.f);
        if (grow < N) {
            va = *reinterpret_cast<const float4*>(x + (size_t)grow * D_DIM + d0);
            vb = *reinterpret_cast<const float4*>(x + (size_t)grow * D_DIM + d0 + 4);
        }
        float sum = ((va.x + va.y) + (va.z + va.w)) + ((vb.x + vb.y) + (vb.z + vb.w));
        float ssq = ((va.x * va.x + va.y * va.y) + (va.z * va.z + va.w * va.w))
                  + ((vb.x * vb.x + vb.y * vb.y) + (vb.z * vb.z + vb.w * vb.w));
        #pragma unroll
        for (int m = 1; m < 16; m <<= 1) {   // 16-lane butterfly (aligned groups)
            sum += __shfl_xor(sum, m, 64);
            ssq += __shfl_xor(ssq, m, 64);
        }
        const float mean = sum * (1.0f / D_DIM);
        const float var  = ssq * (1.0f / D_DIM) - mean * mean;
        const float rstd = rsqrtf(var + 1e-5f);

        float4 ga = *reinterpret_cast<const float4*>(gamma + d0);
        float4 gb = *reinterpret_cast<const float4*>(gamma + d0 + 4);
        float4 ba = *reinterpret_cast<const float4*>(beta + d0);
        float4 bb = *reinterpret_cast<const float4*>(beta + d0 + 4);

        const int wdg = j >> 2;                    // dg of this d-octet
        const int q0  = (j & 3) * 2;               // f4 slot within row segment
        const int ib  = wdg * XPAD + r * 9 + q0;

        s_ln4[ib]     = make_float4((va.x - mean) * rstd * ga.x + ba.x,
                                    (va.y - mean) * rstd * ga.y + ba.y,
                                    (va.z - mean) * rstd * ga.z + ba.z,
                                    (va.w - mean) * rstd * ga.w + ba.w);
        s_ln4[ib + 1] = make_float4((vb.x - mean) * rstd * gb.x + bb.x,
                                    (vb.y - mean) * rstd * gb.y + bb.y,
                                    (vb.z - mean) * rstd * gb.z + bb.z,
                                    (vb.w - mean) * rstd * gb.w + bb.w);
        s_rw4[ib]     = va;
        s_rw4[ib + 1] = vb;
    }
    __syncthreads();      // the only block-wide barrier

    // ---- Phase 2: barrier-free row sweep; weights from registers ----
    #pragma unroll 1      // unroll 2 would exceed the 256-VGPR budget (spill)
    for (int r = 0; r < ROWS; ++r) {
        const int xb = dg * XPAD + r * 9;
        v2f aw = {0.f, 0.f};
        v2f ab = {0.f, 0.f};
        #pragma unroll
        for (int k4 = 0; k4 < 8; ++k4) {
            float4 xl = s_ln4[xb + k4];        // 4-address multicast, conflict-free
            float4 xr = s_rw4[xb + k4];
            float4 a0 = wA[2 * k4],     b0 = wB[2 * k4];
            float4 a1 = wA[2 * k4 + 1], b1 = wB[2 * k4 + 1];

            v2f u, qq, e;
            u  = (v2f){xl.x, xl.y} * (v2f){a0.z, a0.w} - (v2f){a0.x, a0.y};
            qq = u * u;
            e  = (v2f){__builtin_amdgcn_exp2f(-qq.x), __builtin_amdgcn_exp2f(-qq.y)};
            aw += ((qq - C1) * e) * (v2f){b0.x, b0.y};
            ab += (v2f){xr.x, xr.y} * (v2f){b0.z, b0.w};

            u  = (v2f){xl.z, xl.w} * (v2f){a1.z, a1.w} - (v2f){a1.x, a1.y};
            qq = u * u;
            e  = (v2f){__builtin_amdgcn_exp2f(-qq.x), __builtin_amdgcn_exp2f(-qq.y)};
            aw += ((qq - C1) * e) * (v2f){b1.x, b1.y};
            ab += (v2f){xr.z, xr.w} * (v2f){b1.z, b1.w};
        }
        float wav = aw.x + aw.y;
        float bas = ab.x + ab.y;
        // cross-dg reduce (dg = lane bits 4..5): all lanes end with full sums
        wav += __shfl_xor(wav, 16, 64);
        wav += __shfl_xor(wav, 32, 64);
        bas += __shfl_xor(bas, 16, 64);
        bas += __shfl_xor(bas, 32, 64);

        if ((lane < 16) && (row0 + r < N)) {
            float sig = 1.0f / (1.0f + __builtin_amdgcn_exp2f(-LOG2E * bas));
            out[(size_t)(row0 + r) * O_DIM + o] = wav + bas * sig;
        }
    }
}

extern "C" void kernel_launch(void* const* d_in, const int* in_sizes, int n_in,
                              void* d_out, int out_size, void* d_ws, size_t ws_size,
                              hipStream_t stream) {
    const float* x     = (const float*)d_in[0];
    const float* scale = (const float*)d_in[1];
    const float* trans = (const float*)d_in[2];
    const float* ww    = (const float*)d_in[3];
    const float* bw    = (const float*)d_in[4];
    const float* gamma = (const float*)d_in[5];
    const float* beta  = (const float*)d_in[6];
    float* out = (float*)d_out;

    const int N = in_sizes[0] / D_DIM;       // 8192
    const int grid = (N + ROWS - 1) / ROWS;  // 256 -> exactly 1 block/CU

    const size_t ws_needed = (size_t)O_DIM * (D_DIM / 2) * 2 * sizeof(float4); // 256 KB
    if (ws_size >= ws_needed) {
        wavekan_prep<<<(O_DIM * (D_DIM / 2) + 255) / 256, 256, 0, stream>>>(
            scale, trans, ww, bw, (float4*)d_ws);
        wavekan_main<true><<<grid, BLOCK, 0, stream>>>(
            x, scale, trans, ww, bw, gamma, beta, (const float4*)d_ws, out, N);
    } else {
        wavekan_main<false><<<grid, BLOCK, 0, stream>>>(
            x, scale, trans, ww, bw, gamma, beta, nullptr, out, N);
    }
}